// Round 2
// baseline (209.167 us; speedup 1.0000x reference)
//
#include <hip/hip_runtime.h>
#include <hip/hip_bf16.h>

// SelfAttention: B=4, S=4096, Din=768, Dout=64.
// R2: KV-split flash attention — 8 waves/block share 16 q-rows, each wave
//     handles 512 kv positions, block-level (m,l,O) merge in LDS.
//     KV tile 64, XOR-swizzled P tile (row-stride-128B conflict fix).

typedef __attribute__((ext_vector_type(8))) __bf16 bf16x8;
typedef __attribute__((ext_vector_type(4))) float  f32x4;

constexpr int BATCH = 4;
constexpr int SEQ   = 4096;
constexpr int DIN   = 768;
constexpr int NTOT  = 192;          // 3 * 64 packed output features
constexpr int MROWS = BATCH * SEQ;  // 16384
constexpr int WAVES = 8;            // waves per attn block
constexpr int KVT   = 64;           // kv tile per iteration

__device__ __forceinline__ f32x4 mfma16(bf16x8 a, bf16x8 b, f32x4 c) {
    return __builtin_amdgcn_mfma_f32_16x16x32_bf16(a, b, c, 0, 0, 0);
}

// ---------------- k0: pack Wq|Wk|Wv (fp32 [64][768] each) -> bf16 [192][768]
__global__ __launch_bounds__(256) void convert_w(
        const float* __restrict__ Wq, const float* __restrict__ Wk,
        const float* __restrict__ Wv, __bf16* __restrict__ wb) {
    int i = blockIdx.x * 256 + threadIdx.x;
    if (i >= NTOT * DIN) return;
    int n = i / DIN;
    const float* src = (n < 64) ? Wq : (n < 128) ? Wk : Wv;
    wb[i] = (__bf16)src[(n & 63) * DIN + (i % DIN)];
}

// ---------------- k1: q,k,v = x @ W^T   (M=16384, N=192, K=768)
__global__ __launch_bounds__(256) void qkv_proj(
        const float* __restrict__ x, const __bf16* __restrict__ wb,
        __bf16* __restrict__ q, __bf16* __restrict__ k, __bf16* __restrict__ vT) {
    const int wave = threadIdx.x >> 6, lane = threadIdx.x & 63;
    const int lr = lane & 15;
    const int lk = (lane >> 4) * 8;
    const int row = blockIdx.x * 64 + wave * 16 + lr;

    f32x4 acc[12];
#pragma unroll
    for (int t = 0; t < 12; ++t) acc[t] = f32x4{0.f, 0.f, 0.f, 0.f};

    for (int k0 = 0; k0 < DIN; k0 += 32) {
        const float* xp = x + (size_t)row * DIN + k0 + lk;
        float4 xa = *(const float4*)(xp);
        float4 xb = *(const float4*)(xp + 4);
        bf16x8 af;
        af[0] = (__bf16)xa.x; af[1] = (__bf16)xa.y; af[2] = (__bf16)xa.z; af[3] = (__bf16)xa.w;
        af[4] = (__bf16)xb.x; af[5] = (__bf16)xb.y; af[6] = (__bf16)xb.z; af[7] = (__bf16)xb.w;
#pragma unroll
        for (int t = 0; t < 12; ++t) {
            bf16x8 bf = *(const bf16x8*)(wb + (size_t)(t * 16 + lr) * DIN + k0 + lk);
            acc[t] = mfma16(af, bf, acc[t]);
        }
    }

    const int orow = blockIdx.x * 64 + wave * 16 + (lane >> 4) * 4;
#pragma unroll
    for (int t = 0; t < 12; ++t) {
        int n = t * 16 + lr;
#pragma unroll
        for (int r = 0; r < 4; ++r) {
            int m = orow + r;
            __bf16 hv = (__bf16)acc[t][r];
            if (n < 64) {
                q[(size_t)m * 64 + n] = hv;
            } else if (n < 128) {
                k[(size_t)m * 64 + (n - 64)] = hv;
            } else {
                int b = m >> 12, s = m & (SEQ - 1);
                vT[(size_t)b * 64 * SEQ + (size_t)(n - 128) * SEQ + s] = hv;
            }
        }
    }
}

// ---------------- k2: flash attention, KV-split within block.
// grid = (SEQ/16, BATCH), block = 512 (8 waves). All waves share the same
// 16 q-rows; wave w covers kv in [w*512, (w+1)*512). Block-level merge.
__global__ __launch_bounds__(512, 8) void attn(
        const __bf16* __restrict__ q, const __bf16* __restrict__ k,
        const __bf16* __restrict__ vT, float* __restrict__ out) {
    const int tid  = threadIdx.x;
    const int wave = tid >> 6, lane = tid & 63;
    const int b  = blockIdx.y;
    const int q0 = blockIdx.x * 16;
    const int lr = lane & 15;          // C col / A row lane index
    const int g  = lane >> 4;          // 16-lane group
    const int lk = g * 8;              // k-offset within a 32-wide MFMA K step

    const __bf16* qp = q  + (size_t)b * SEQ * 64;
    const __bf16* kp = k  + (size_t)b * SEQ * 64;
    const __bf16* vp = vT + (size_t)b * 64 * SEQ;

    // Merge scratch; each wave's P tile aliases its own o_lds region
    // (P: 16 rows x 128 B, XOR-swizzled; o: 16 x 64 fp32).
    __shared__ __align__(16) float o_lds[WAVES][16][64];   // 32 KiB
    __shared__ float m_lds[WAVES][16];
    __shared__ float l_lds[WAVES][16];
    char* pw = (char*)&o_lds[wave][0][0];

    // Q fragments (loop-invariant)
    bf16x8 qf0 = *(const bf16x8*)(qp + (size_t)(q0 + lr) * 64 + lk);
    bf16x8 qf1 = *(const bf16x8*)(qp + (size_t)(q0 + lr) * 64 + 32 + lk);

    f32x4 acc_o[4];
#pragma unroll
    for (int t = 0; t < 4; ++t) acc_o[t] = f32x4{0.f, 0.f, 0.f, 0.f};
    float m_run[4], l_run[4];
#pragma unroll
    for (int r = 0; r < 4; ++r) { m_run[r] = -1e30f; l_run[r] = 0.f; }

    const int kv_base = wave * (SEQ / WAVES);
    for (int it = 0; it < (SEQ / WAVES) / KVT; ++it) {
        const int kv0 = kv_base + it * KVT;

        // ---- S = Q K^T (four 16x16 kv-subtiles)
        f32x4 s[4];
#pragma unroll
        for (int j = 0; j < 4; ++j) {
            const __bf16* kr = kp + (size_t)(kv0 + j * 16 + lr) * 64 + lk;
            bf16x8 kf0 = *(const bf16x8*)(kr);
            bf16x8 kf1 = *(const bf16x8*)(kr + 32);
            f32x4 a = f32x4{0.f, 0.f, 0.f, 0.f};
            a = mfma16(qf0, kf0, a);
            a = mfma16(qf1, kf1, a);
            s[j] = a;
        }

        // ---- online softmax over 64 cols (per q-row = g*4+r)
        float al[4];
#pragma unroll
        for (int r = 0; r < 4; ++r) {
            float v0 = s[0][r] * 0.125f, v1 = s[1][r] * 0.125f;
            float v2 = s[2][r] * 0.125f, v3 = s[3][r] * 0.125f;
            float mx = fmaxf(fmaxf(v0, v1), fmaxf(v2, v3));
            mx = fmaxf(mx, __shfl_xor(mx, 1));
            mx = fmaxf(mx, __shfl_xor(mx, 2));
            mx = fmaxf(mx, __shfl_xor(mx, 4));
            mx = fmaxf(mx, __shfl_xor(mx, 8));
            float mn = fmaxf(m_run[r], mx);
            al[r] = __expf(m_run[r] - mn);
            m_run[r] = mn;
            float p0 = __expf(v0 - mn), p1 = __expf(v1 - mn);
            float p2 = __expf(v2 - mn), p3 = __expf(v3 - mn);
            float su = p0 + p1 + p2 + p3;
            su += __shfl_xor(su, 1);
            su += __shfl_xor(su, 2);
            su += __shfl_xor(su, 4);
            su += __shfl_xor(su, 8);
            l_run[r] = l_run[r] * al[r] + su;

            // P -> LDS, XOR-swizzled: byte = row*128 + (colbyte ^ ((row&7)<<4))
            const int row = g * 4 + r;
            const int rx  = (row & 7) << 4;
            char* rowp = pw + row * 128;
            *(__bf16*)(rowp + (((0 * 32) + lr * 2) ^ rx)) = (__bf16)p0;
            *(__bf16*)(rowp + (((1 * 32) + lr * 2) ^ rx)) = (__bf16)p1;
            *(__bf16*)(rowp + (((2 * 32) + lr * 2) ^ rx)) = (__bf16)p2;
            *(__bf16*)(rowp + (((3 * 32) + lr * 2) ^ rx)) = (__bf16)p3;
        }
        asm volatile("s_waitcnt lgkmcnt(0)" ::: "memory");

        // ---- O = O*alpha + P V   (2 K-steps x 4 d-tiles)
#pragma unroll
        for (int t = 0; t < 4; ++t)
#pragma unroll
            for (int r = 0; r < 4; ++r) acc_o[t][r] *= al[r];
#pragma unroll
        for (int ks = 0; ks < 2; ++ks) {
            bf16x8 pf = *(const bf16x8*)(pw + lr * 128 +
                                         ((ks * 64 + g * 16) ^ ((lr & 7) << 4)));
#pragma unroll
            for (int t = 0; t < 4; ++t) {
                bf16x8 vf = *(const bf16x8*)(vp + (size_t)(t * 16 + lr) * SEQ +
                                             kv0 + ks * 32 + lk);
                acc_o[t] = mfma16(pf, vf, acc_o[t]);
            }
        }
    }

    // ---- publish this wave's partial (m, l, O) — o_lds overwrites own P tile
    asm volatile("s_waitcnt lgkmcnt(0)" ::: "memory");
#pragma unroll
    for (int t = 0; t < 4; ++t)
#pragma unroll
        for (int r = 0; r < 4; ++r)
            o_lds[wave][g * 4 + r][t * 16 + lr] = acc_o[t][r];
    if (lr == 0) {
#pragma unroll
        for (int r = 0; r < 4; ++r) {
            m_lds[wave][g * 4 + r] = m_run[r];
            l_lds[wave][g * 4 + r] = l_run[r];
        }
    }
    __syncthreads();

    // ---- merge: M = max_w m_w; scale_w = exp(m_w - M); L = sum l_w*scale_w
    if (tid < 16) {
        float M = -1e30f;
#pragma unroll
        for (int w = 0; w < WAVES; ++w) M = fmaxf(M, m_lds[w][tid]);
        float L = 0.f;
#pragma unroll
        for (int w = 0; w < WAVES; ++w) {
            float sc = __expf(m_lds[w][tid] - M);
            m_lds[w][tid] = sc;
            L += l_lds[w][tid] * sc;
        }
        l_lds[0][tid] = 1.f / L;
    }
    __syncthreads();

    // ---- out[row][col] = (sum_w o_w * scale_w) / L   (1024 elems, 2/thread)
    float* ob = out + ((size_t)b * SEQ + q0) * 64;
#pragma unroll
    for (int e = 0; e < 2; ++e) {
        int idx = tid + e * 512;
        int row = idx >> 6, col = idx & 63;
        float a = 0.f;
#pragma unroll
        for (int w = 0; w < WAVES; ++w) a += o_lds[w][row][col] * m_lds[w][row];
        ob[(size_t)row * 64 + col] = a * l_lds[0][row];
    }
}

extern "C" void kernel_launch(void* const* d_in, const int* in_sizes, int n_in,
                              void* d_out, int out_size, void* d_ws, size_t ws_size,
                              hipStream_t stream) {
    const float* x  = (const float*)d_in[0];
    const float* Wq = (const float*)d_in[1];
    const float* Wk = (const float*)d_in[2];
    const float* Wv = (const float*)d_in[3];
    float* out = (float*)d_out;

    char* ws = (char*)d_ws;
    __bf16* wb = (__bf16*)(ws);
    __bf16* qb = (__bf16*)(ws + 294912);
    __bf16* kb = (__bf16*)(ws + 294912 + 2097152);
    __bf16* vT = (__bf16*)(ws + 294912 + 2u * 2097152);

    convert_w<<<dim3((NTOT * DIN + 255) / 256), dim3(256), 0, stream>>>(Wq, Wk, Wv, wb);
    qkv_proj<<<dim3(MROWS / 64), dim3(256), 0, stream>>>(x, wb, qb, kb, vT);
    attn<<<dim3(SEQ / 16, BATCH), dim3(512), 0, stream>>>(qb, kb, vT, out);
}

// Round 3
// 171.341 us; speedup vs baseline: 1.2208x; 1.2208x over previous
//
#include <hip/hip_runtime.h>
#include <hip/hip_bf16.h>

// SelfAttention: B=4, S=4096, Din=768, Dout=64.
// R3: same KV-split structure as R2, but __launch_bounds__(512,4) instead of
//     (512,8). R2's min-8-waves forced a 64-VGPR cap -> VGPR_Count=32 with
//     massive scratch spills (WRITE_SIZE 128MB, FETCH 244MB). 128-VGPR cap
//     holds all live state (~70 regs) in registers at 4 waves/SIMD.

typedef __attribute__((ext_vector_type(8))) __bf16 bf16x8;
typedef __attribute__((ext_vector_type(4))) float  f32x4;

constexpr int BATCH = 4;
constexpr int SEQ   = 4096;
constexpr int DIN   = 768;
constexpr int NTOT  = 192;          // 3 * 64 packed output features
constexpr int MROWS = BATCH * SEQ;  // 16384
constexpr int WAVES = 8;            // waves per attn block
constexpr int KVT   = 64;           // kv tile per iteration

__device__ __forceinline__ f32x4 mfma16(bf16x8 a, bf16x8 b, f32x4 c) {
    return __builtin_amdgcn_mfma_f32_16x16x32_bf16(a, b, c, 0, 0, 0);
}

// ---------------- k0: pack Wq|Wk|Wv (fp32 [64][768] each) -> bf16 [192][768]
__global__ __launch_bounds__(256) void convert_w(
        const float* __restrict__ Wq, const float* __restrict__ Wk,
        const float* __restrict__ Wv, __bf16* __restrict__ wb) {
    int i = blockIdx.x * 256 + threadIdx.x;
    if (i >= NTOT * DIN) return;
    int n = i / DIN;
    const float* src = (n < 64) ? Wq : (n < 128) ? Wk : Wv;
    wb[i] = (__bf16)src[(n & 63) * DIN + (i % DIN)];
}

// ---------------- k1: q,k,v = x @ W^T   (M=16384, N=192, K=768)
__global__ __launch_bounds__(256) void qkv_proj(
        const float* __restrict__ x, const __bf16* __restrict__ wb,
        __bf16* __restrict__ q, __bf16* __restrict__ k, __bf16* __restrict__ vT) {
    const int wave = threadIdx.x >> 6, lane = threadIdx.x & 63;
    const int lr = lane & 15;
    const int lk = (lane >> 4) * 8;
    const int row = blockIdx.x * 64 + wave * 16 + lr;

    f32x4 acc[12];
#pragma unroll
    for (int t = 0; t < 12; ++t) acc[t] = f32x4{0.f, 0.f, 0.f, 0.f};

    for (int k0 = 0; k0 < DIN; k0 += 32) {
        const float* xp = x + (size_t)row * DIN + k0 + lk;
        float4 xa = *(const float4*)(xp);
        float4 xb = *(const float4*)(xp + 4);
        bf16x8 af;
        af[0] = (__bf16)xa.x; af[1] = (__bf16)xa.y; af[2] = (__bf16)xa.z; af[3] = (__bf16)xa.w;
        af[4] = (__bf16)xb.x; af[5] = (__bf16)xb.y; af[6] = (__bf16)xb.z; af[7] = (__bf16)xb.w;
#pragma unroll
        for (int t = 0; t < 12; ++t) {
            bf16x8 bf = *(const bf16x8*)(wb + (size_t)(t * 16 + lr) * DIN + k0 + lk);
            acc[t] = mfma16(af, bf, acc[t]);
        }
    }

    const int orow = blockIdx.x * 64 + wave * 16 + (lane >> 4) * 4;
#pragma unroll
    for (int t = 0; t < 12; ++t) {
        int n = t * 16 + lr;
#pragma unroll
        for (int r = 0; r < 4; ++r) {
            int m = orow + r;
            __bf16 hv = (__bf16)acc[t][r];
            if (n < 64) {
                q[(size_t)m * 64 + n] = hv;
            } else if (n < 128) {
                k[(size_t)m * 64 + (n - 64)] = hv;
            } else {
                int b = m >> 12, s = m & (SEQ - 1);
                vT[(size_t)b * 64 * SEQ + (size_t)(n - 128) * SEQ + s] = hv;
            }
        }
    }
}

// ---------------- k2: flash attention, KV-split within block.
// grid = (SEQ/16, BATCH), block = 512 (8 waves). All waves share the same
// 16 q-rows; wave w covers kv in [w*512, (w+1)*512). Block-level merge.
__global__ __launch_bounds__(512, 4) void attn(
        const __bf16* __restrict__ q, const __bf16* __restrict__ k,
        const __bf16* __restrict__ vT, float* __restrict__ out) {
    const int tid  = threadIdx.x;
    const int wave = tid >> 6, lane = tid & 63;
    const int b  = blockIdx.y;
    const int q0 = blockIdx.x * 16;
    const int lr = lane & 15;          // C col / A row lane index
    const int g  = lane >> 4;          // 16-lane group
    const int lk = g * 8;              // k-offset within a 32-wide MFMA K step

    const __bf16* qp = q  + (size_t)b * SEQ * 64;
    const __bf16* kp = k  + (size_t)b * SEQ * 64;
    const __bf16* vp = vT + (size_t)b * 64 * SEQ;

    // Merge scratch; each wave's P tile aliases its own o_lds region
    // (P: 16 rows x 128 B, XOR-swizzled; o: 16 x 64 fp32).
    __shared__ __align__(16) float o_lds[WAVES][16][64];   // 32 KiB
    __shared__ float m_lds[WAVES][16];
    __shared__ float l_lds[WAVES][16];
    char* pw = (char*)&o_lds[wave][0][0];

    // Q fragments (loop-invariant)
    bf16x8 qf0 = *(const bf16x8*)(qp + (size_t)(q0 + lr) * 64 + lk);
    bf16x8 qf1 = *(const bf16x8*)(qp + (size_t)(q0 + lr) * 64 + 32 + lk);

    f32x4 acc_o[4];
#pragma unroll
    for (int t = 0; t < 4; ++t) acc_o[t] = f32x4{0.f, 0.f, 0.f, 0.f};
    float m_run[4], l_run[4];
#pragma unroll
    for (int r = 0; r < 4; ++r) { m_run[r] = -1e30f; l_run[r] = 0.f; }

    const int kv_base = wave * (SEQ / WAVES);
    for (int it = 0; it < (SEQ / WAVES) / KVT; ++it) {
        const int kv0 = kv_base + it * KVT;

        // ---- S = Q K^T (four 16x16 kv-subtiles)
        f32x4 s[4];
#pragma unroll
        for (int j = 0; j < 4; ++j) {
            const __bf16* kr = kp + (size_t)(kv0 + j * 16 + lr) * 64 + lk;
            bf16x8 kf0 = *(const bf16x8*)(kr);
            bf16x8 kf1 = *(const bf16x8*)(kr + 32);
            f32x4 a = f32x4{0.f, 0.f, 0.f, 0.f};
            a = mfma16(qf0, kf0, a);
            a = mfma16(qf1, kf1, a);
            s[j] = a;
        }

        // ---- online softmax over 64 cols (per q-row = g*4+r)
        float al[4];
#pragma unroll
        for (int r = 0; r < 4; ++r) {
            float v0 = s[0][r] * 0.125f, v1 = s[1][r] * 0.125f;
            float v2 = s[2][r] * 0.125f, v3 = s[3][r] * 0.125f;
            float mx = fmaxf(fmaxf(v0, v1), fmaxf(v2, v3));
            mx = fmaxf(mx, __shfl_xor(mx, 1));
            mx = fmaxf(mx, __shfl_xor(mx, 2));
            mx = fmaxf(mx, __shfl_xor(mx, 4));
            mx = fmaxf(mx, __shfl_xor(mx, 8));
            float mn = fmaxf(m_run[r], mx);
            al[r] = __expf(m_run[r] - mn);
            m_run[r] = mn;
            float p0 = __expf(v0 - mn), p1 = __expf(v1 - mn);
            float p2 = __expf(v2 - mn), p3 = __expf(v3 - mn);
            float su = p0 + p1 + p2 + p3;
            su += __shfl_xor(su, 1);
            su += __shfl_xor(su, 2);
            su += __shfl_xor(su, 4);
            su += __shfl_xor(su, 8);
            l_run[r] = l_run[r] * al[r] + su;

            // P -> LDS, XOR-swizzled: byte = row*128 + (colbyte ^ ((row&7)<<4))
            const int row = g * 4 + r;
            const int rx  = (row & 7) << 4;
            char* rowp = pw + row * 128;
            *(__bf16*)(rowp + (((0 * 32) + lr * 2) ^ rx)) = (__bf16)p0;
            *(__bf16*)(rowp + (((1 * 32) + lr * 2) ^ rx)) = (__bf16)p1;
            *(__bf16*)(rowp + (((2 * 32) + lr * 2) ^ rx)) = (__bf16)p2;
            *(__bf16*)(rowp + (((3 * 32) + lr * 2) ^ rx)) = (__bf16)p3;
        }
        asm volatile("s_waitcnt lgkmcnt(0)" ::: "memory");

        // ---- O = O*alpha + P V   (2 K-steps x 4 d-tiles)
#pragma unroll
        for (int t = 0; t < 4; ++t)
#pragma unroll
            for (int r = 0; r < 4; ++r) acc_o[t][r] *= al[r];
#pragma unroll
        for (int ks = 0; ks < 2; ++ks) {
            bf16x8 pf = *(const bf16x8*)(pw + lr * 128 +
                                         ((ks * 64 + g * 16) ^ ((lr & 7) << 4)));
#pragma unroll
            for (int t = 0; t < 4; ++t) {
                bf16x8 vf = *(const bf16x8*)(vp + (size_t)(t * 16 + lr) * SEQ +
                                             kv0 + ks * 32 + lk);
                acc_o[t] = mfma16(pf, vf, acc_o[t]);
            }
        }
    }

    // ---- publish this wave's partial (m, l, O) — o_lds overwrites own P tile
    asm volatile("s_waitcnt lgkmcnt(0)" ::: "memory");
#pragma unroll
    for (int t = 0; t < 4; ++t)
#pragma unroll
        for (int r = 0; r < 4; ++r)
            o_lds[wave][g * 4 + r][t * 16 + lr] = acc_o[t][r];
    if (lr == 0) {
#pragma unroll
        for (int r = 0; r < 4; ++r) {
            m_lds[wave][g * 4 + r] = m_run[r];
            l_lds[wave][g * 4 + r] = l_run[r];
        }
    }
    __syncthreads();

    // ---- merge: M = max_w m_w; scale_w = exp(m_w - M); L = sum l_w*scale_w
    if (tid < 16) {
        float M = -1e30f;
#pragma unroll
        for (int w = 0; w < WAVES; ++w) M = fmaxf(M, m_lds[w][tid]);
        float L = 0.f;
#pragma unroll
        for (int w = 0; w < WAVES; ++w) {
            float sc = __expf(m_lds[w][tid] - M);
            m_lds[w][tid] = sc;
            L += l_lds[w][tid] * sc;
        }
        l_lds[0][tid] = 1.f / L;
    }
    __syncthreads();

    // ---- out[row][col] = (sum_w o_w * scale_w) / L   (1024 elems, 2/thread)
    float* ob = out + ((size_t)b * SEQ + q0) * 64;
#pragma unroll
    for (int e = 0; e < 2; ++e) {
        int idx = tid + e * 512;
        int row = idx >> 6, col = idx & 63;
        float a = 0.f;
#pragma unroll
        for (int w = 0; w < WAVES; ++w) a += o_lds[w][row][col] * m_lds[w][row];
        ob[(size_t)row * 64 + col] = a * l_lds[0][row];
    }
}

extern "C" void kernel_launch(void* const* d_in, const int* in_sizes, int n_in,
                              void* d_out, int out_size, void* d_ws, size_t ws_size,
                              hipStream_t stream) {
    const float* x  = (const float*)d_in[0];
    const float* Wq = (const float*)d_in[1];
    const float* Wk = (const float*)d_in[2];
    const float* Wv = (const float*)d_in[3];
    float* out = (float*)d_out;

    char* ws = (char*)d_ws;
    __bf16* wb = (__bf16*)(ws);
    __bf16* qb = (__bf16*)(ws + 294912);
    __bf16* kb = (__bf16*)(ws + 294912 + 2097152);
    __bf16* vT = (__bf16*)(ws + 294912 + 2u * 2097152);

    convert_w<<<dim3((NTOT * DIN + 255) / 256), dim3(256), 0, stream>>>(Wq, Wk, Wv, wb);
    qkv_proj<<<dim3(MROWS / 64), dim3(256), 0, stream>>>(x, wb, qb, kb, vT);
    attn<<<dim3(SEQ / 16, BATCH), dim3(512), 0, stream>>>(qb, kb, vT, out);
}